// Round 14
// baseline (169.060 us; speedup 1.0000x reference)
//
#include <hip/hip_runtime.h>
#include <hip/hip_fp16.h>
#include <stdint.h>

#ifndef JAX_PARTITIONABLE
#define JAX_PARTITIONABLE 1   // JAX >= 0.5 default threefry_partitionable
#endif

typedef _Float16 f16x8 __attribute__((ext_vector_type(8)));
typedef float    f32x4 __attribute__((ext_vector_type(4)));

// ---------------- problem sizes ----------------
static constexpr int BZ   = 8;
static constexpr int QD   = 512;
static constexpr int DIM  = 1024;
static constexpr int I2   = 64;
static constexpr int TOPJ = 128;
static constexpr int NROW = 16384;
static constexpr int NCT  = 4;      // 1024 / 256 col-tiles

// ---------------- ws layout ----------------
// ushort region, ROW-MAJOR interleaved:
//   AI[row][2048]: per row 32 kc-chunks x (32 hi | 32 lo) ushorts = 4KB/row
//   WI[row][2048]: same for the weight matrix
static constexpr size_t EAI = 0;                               // 16384*2048
static constexpr size_t EWI = (size_t)33554432;                // 1024*2048
// float region starts at float index 17,825,792
static constexpr size_t FQN   = 17825792;            // (unused, kept)
static constexpr size_t FSF   = FQN + 4096;          // (unused, kept)
static constexpr size_t FYS   = FSF + 32768;         // 8*1024
static constexpr size_t FYR   = FYS + 8192;          // 8*1024
static constexpr size_t FY2   = FYR + 8192;          // 8*4*1024
static constexpr size_t FGQ   = FY2 + 32768;         // 8*1024
static constexpr size_t FSG   = FGQ + 8192;          // 8
static constexpr size_t FCL   = FSG + 8;             // 8
static constexpr size_t FMS   = FCL + 8;             // 8*2*4
static constexpr size_t FP2   = FMS + 64;            // (unused, kept)
static constexpr size_t FPART = FP2 + 16384;         // NCT*16384*3

// ---------------- threefry2x32 (JAX-exact) ----------------
__device__ __forceinline__ uint32_t rotl32(uint32_t v, int d){ return (v << d) | (v >> (32 - d)); }

__device__ __forceinline__ void tf2x32(uint32_t k0, uint32_t k1, uint32_t x0, uint32_t x1,
                                       uint32_t& o0, uint32_t& o1){
  const uint32_t ks2 = k0 ^ k1 ^ 0x1BD11BDAu;
  x0 += k0; x1 += k1;
#define TFR(r) x0 += x1; x1 = rotl32(x1, r); x1 ^= x0;
  TFR(13) TFR(15) TFR(26) TFR(6)
  x0 += k1;  x1 += ks2 + 1u;
  TFR(17) TFR(29) TFR(16) TFR(24)
  x0 += ks2; x1 += k0 + 2u;
  TFR(13) TFR(15) TFR(26) TFR(6)
  x0 += k0;  x1 += k1 + 3u;
  TFR(17) TFR(29) TFR(16) TFR(24)
  x0 += k1;  x1 += ks2 + 4u;
  TFR(13) TFR(15) TFR(26) TFR(6)
  x0 += ks2; x1 += k0 + 5u;
#undef TFR
  o0 = x0; o1 = x1;
}

__device__ __forceinline__ void jax_keys(uint32_t& k1a, uint32_t& k1b, uint32_t& k2a, uint32_t& k2b){
#if JAX_PARTITIONABLE
  uint32_t a,b,c,d;
  tf2x32(0u, 42u, 0u, 0u, a, b);
  tf2x32(0u, 42u, 0u, 1u, c, d);
  k1a = a; k1b = b; k2a = c; k2b = d;
#else
  uint32_t a,b,c,d;
  tf2x32(0u, 42u, 0u, 2u, a, b);
  tf2x32(0u, 42u, 1u, 3u, c, d);
  k1a = a; k1b = c; k2a = b; k2b = d;
#endif
}

__device__ __forceinline__ float jax_uniform(uint32_t ka, uint32_t kb, uint32_t idx, uint32_t half_n){
  uint32_t o0, o1, bits;
#if JAX_PARTITIONABLE
  (void)half_n;
  tf2x32(ka, kb, 0u, idx, o0, o1);
  bits = o0 ^ o1;
#else
  if (idx < half_n){ tf2x32(ka, kb, idx, idx + half_n, o0, o1); bits = o0; }
  else             { tf2x32(ka, kb, idx - half_n, idx, o0, o1); bits = o1; }
#endif
  float f = __uint_as_float((bits >> 9) | 0x3f800000u) - 1.0f;
  f = f + 1e-20f;
  return fmaxf(f, 1e-20f);
}

// ---------------- block reductions (wave shuffle + 4-slot LDS, 2 barriers) ----
__device__ __forceinline__ float blk_sum(float v, float* red){
  __syncthreads();
  #pragma unroll
  for (int m = 32; m >= 1; m >>= 1) v += __shfl_xor(v, m);
  if ((threadIdx.x & 63) == 0) red[threadIdx.x >> 6] = v;
  __syncthreads();
  return red[0] + red[1] + red[2] + red[3];
}
__device__ __forceinline__ float blk_max(float v, float* red){
  __syncthreads();
  #pragma unroll
  for (int m = 32; m >= 1; m >>= 1) v = fmaxf(v, __shfl_xor(v, m));
  if ((threadIdx.x & 63) == 0) red[threadIdx.x >> 6] = v;
  __syncthreads();
  return fmaxf(fmaxf(red[0], red[1]), fmaxf(red[2], red[3]));
}

// ---------------- fp16 split helpers ----------------
__device__ __forceinline__ unsigned short f2h(float x){
  return __half_as_ushort(__float2half(x));
}
__device__ __forceinline__ float h2f(unsigned short u){
  return __half2float(__ushort_as_half(u));
}

// ---------------- async global->LDS (16B/lane) ----------------
__device__ __forceinline__ void gl_lds16(const void* g, void* l){
  __builtin_amdgcn_global_load_lds((const __attribute__((address_space(1))) void*)g,
                                   (__attribute__((address_space(3))) void*)l, 16, 0, 0);
}

// ================= K1: norms (in-block) + distributed matvecs =================
__global__ __launch_bounds__(256) void k_matvec(
    const float* __restrict__ qf, const float* __restrict__ vcls,
    const float* __restrict__ sWq, const float* __restrict__ sbq,
    const float* __restrict__ rWq, const float* __restrict__ rbq,
    const float* __restrict__ sWk, const float* __restrict__ sbk,
    float* __restrict__ ws)
{
  const int bid = blockIdx.x;
  const int b = bid >> 5, ch = bid & 31;
  const int tid = threadIdx.x;
  __shared__ float red[4];
  __shared__ float qn[QD];
  __shared__ float sf[4][DIM];

  // q-norm
  {
    float q0 = qf[b * QD + tid];
    float q1 = qf[b * QD + 256 + tid];
    float ss = blk_sum(q0*q0 + q1*q1, red);
    float nrm = sqrtf(ss);
    qn[tid] = q0 / nrm;
    qn[tid + 256] = q1 / nrm;
  }
  // seg_feat (mean of 4 L2-normalized frames per segment)
  {
    float sfr[4][4];
    #pragma unroll
    for (int c = 0; c < 4; ++c)
      #pragma unroll
      for (int r = 0; r < 4; ++r) sfr[c][r] = 0.f;
    for (int f = 0; f < 16; ++f){
      float v[4]; float s2 = 0.f;
      #pragma unroll
      for (int r = 0; r < 4; ++r){
        v[r] = vcls[((size_t)(b * 16 + f)) * DIM + tid + (r << 8)];
        s2 += v[r] * v[r];
      }
      float s = blk_sum(s2, red);
      float n2 = sqrtf(s);
      const int c = f >> 2;
      #pragma unroll
      for (int r = 0; r < 4; ++r) sfr[c][r] += v[r] / n2;
    }
    #pragma unroll
    for (int c = 0; c < 4; ++c)
      #pragma unroll
      for (int r = 0; r < 4; ++r)
        sf[c][tid + (r << 8)] = sfr[c][r] * 0.25f;
  }
  __syncthreads();

  const int di = tid >> 3, sub = tid & 7;
  const int d = ch * 32 + di;

  {
    const float* wr = sWq + (size_t)d * QD + sub * 64;
    const float* qq = qn + sub * 64;
    float a = 0.f;
    #pragma unroll
    for (int e = 0; e < 64; e += 4){
      float4 w4 = *(const float4*)(wr + e);
      a += qq[e]*w4.x + qq[e+1]*w4.y + qq[e+2]*w4.z + qq[e+3]*w4.w;
    }
    a += __shfl_xor(a, 1); a += __shfl_xor(a, 2); a += __shfl_xor(a, 4);
    if (sub == 0) ws[FYS + (size_t)b * DIM + d] = a + sbq[d];
  }
  {
    const float* wr = rWq + (size_t)d * QD + sub * 64;
    const float* qq = qn + sub * 64;
    float a = 0.f;
    #pragma unroll
    for (int e = 0; e < 64; e += 4){
      float4 w4 = *(const float4*)(wr + e);
      a += qq[e]*w4.x + qq[e+1]*w4.y + qq[e+2]*w4.z + qq[e+3]*w4.w;
    }
    a += __shfl_xor(a, 1); a += __shfl_xor(a, 2); a += __shfl_xor(a, 4);
    if (sub == 0) ws[FYR + (size_t)b * DIM + d] = a + rbq[d];
  }
  for (int c = 0; c < 4; ++c){
    const float* wr = sWk + (size_t)d * DIM + sub * 128;
    const float* qq = &sf[c][sub * 128];
    float a = 0.f;
    #pragma unroll
    for (int e = 0; e < 128; e += 4){
      float4 w4 = *(const float4*)(wr + e);
      a += qq[e]*w4.x + qq[e+1]*w4.y + qq[e+2]*w4.z + qq[e+3]*w4.w;
    }
    a += __shfl_xor(a, 1); a += __shfl_xor(a, 2); a += __shfl_xor(a, 4);
    if (sub == 0) ws[FY2 + ((size_t)(b * 4 + c)) * DIM + d] = a + sbk[d];
  }
}

// ================= K2: LN finishers + seg softmax/gumbel masks =================
__global__ __launch_bounds__(256) void k_post(
    const float* __restrict__ slnqg, const float* __restrict__ slnqb,
    const float* __restrict__ rlnqg, const float* __restrict__ rlnqb,
    const float* __restrict__ rlnkg, const float* __restrict__ rlnkb,
    const float* __restrict__ slnkg, const float* __restrict__ slnkb,
    float* __restrict__ ws)
{
  const int b = blockIdx.x, tid = threadIdx.x;
  __shared__ float red[4];
  __shared__ float qps[DIM];
  __shared__ float lg[4];

  {
    float y[4];
    #pragma unroll
    for (int r = 0; r < 4; ++r) y[r] = ws[FYS + (size_t)b * DIM + tid + (r << 8)];
    float S = blk_sum(y[0]+y[1]+y[2]+y[3], red);
    float mu = S * (1.f / 1024.f);
    float pv = 0.f;
    #pragma unroll
    for (int r = 0; r < 4; ++r){ float dv = y[r]-mu; pv += dv*dv; }
    float V = blk_sum(pv, red);
    float sig = sqrtf(V * (1.f / 1024.f) + 1e-12f);
    #pragma unroll
    for (int r = 0; r < 4; ++r){
      const int d = tid + (r << 8);
      qps[d] = (y[r]-mu)/sig * slnqg[d] + slnqb[d];
    }
  }
  __syncthreads();

  {
    float y[4];
    #pragma unroll
    for (int r = 0; r < 4; ++r) y[r] = ws[FYR + (size_t)b * DIM + tid + (r << 8)];
    float S = blk_sum(y[0]+y[1]+y[2]+y[3], red);
    float mu = S * (1.f / 1024.f);
    float pv = 0.f;
    #pragma unroll
    for (int r = 0; r < 4; ++r){ float dv = y[r]-mu; pv += dv*dv; }
    float V = blk_sum(pv, red);
    float sig = sqrtf(V * (1.f / 1024.f) + 1e-12f);
    float sg = 0.f, cl = 0.f;
    #pragma unroll
    for (int r = 0; r < 4; ++r){
      const int d = tid + (r << 8);
      float o = (y[r]-mu)/sig * rlnqg[d] + rlnqb[d];
      float gv = rlnkg[d] * o;
      ws[FGQ + (size_t)b * DIM + d] = gv;
      sg += gv;
      cl += rlnkb[d] * o;
    }
    float SG = blk_sum(sg, red);
    float CL = blk_sum(cl, red);
    if (tid == 0){ ws[FSG + b] = SG; ws[FCL + b] = CL; }
  }

  for (int c = 0; c < 4; ++c){
    float y[4];
    #pragma unroll
    for (int r = 0; r < 4; ++r) y[r] = ws[FY2 + ((size_t)(b * 4 + c)) * DIM + tid + (r << 8)];
    float S = blk_sum(y[0]+y[1]+y[2]+y[3], red);
    float mu = S * (1.f / 1024.f);
    float pv = 0.f;
    #pragma unroll
    for (int r = 0; r < 4; ++r){ float dv = y[r]-mu; pv += dv*dv; }
    float V = blk_sum(pv, red);
    float sig = sqrtf(V * (1.f / 1024.f) + 1e-12f);
    float lp = 0.f;
    #pragma unroll
    for (int r = 0; r < 4; ++r){
      const int d = tid + (r << 8);
      float kp = (y[r]-mu)/sig * slnkg[d] + slnkb[d];
      lp += kp * qps[d];
    }
    float L = blk_sum(lp, red);
    if (tid == 0) lg[c] = L;
  }
  __syncthreads();

  if (tid == 0){
    float m = fmaxf(fmaxf(lg[0], lg[1]), fmaxf(lg[2], lg[3]));
    float e[4], s = 0.f;
    #pragma unroll
    for (int c = 0; c < 4; ++c){ e[c] = expf(lg[c] - m); s += e[c]; }
    float probs[4];
    #pragma unroll
    for (int c = 0; c < 4; ++c) probs[c] = e[c] / s;
    uint32_t k1a, k1b, k2a, k2b;
    jax_keys(k1a, k1b, k2a, k2b);
    for (int t = 0; t < 2; ++t){
      float x[4];
      #pragma unroll
      for (int c = 0; c < 4; ++c){
        float u = jax_uniform(k1a, k1b, (uint32_t)(b * 8 + t * 4 + c), 32u);
        float gmb = -logf(-logf(u));
        x[c] = (probs[c] + gmb) / 1e-6f;
      }
      float xm = fmaxf(fmaxf(x[0], x[1]), fmaxf(x[2], x[3]));
      float w[4], sw = 0.f;
      #pragma unroll
      for (int c = 0; c < 4; ++c){ w[c] = expf(x[c] - xm); sw += w[c]; }
      #pragma unroll
      for (int c = 0; c < 4; ++c) ws[FMS + b * 8 + t * 4 + c] = w[c] / sw;
    }
  }
}

// ================= K3: sel rows -> AI; tail: W -> WI (8 rows/block, fat) =======
__global__ __launch_bounds__(256) void k_sel(const float* __restrict__ E,
                                             const float* __restrict__ W,
                                             float* __restrict__ ws)
{
  const int blk = blockIdx.x;
  const int th = threadIdx.x;
  const int kc = th >> 3;              // 0..31
  const int c  = (th & 7) >> 1;        // 16B chunk within 32-elem half
  const int pos = (th & 1) * 4;
  const int d = th << 2;

  if (blk < 2048){
    const int r0 = blk * 8;            // 8 rows, all in pseudo-batch i
    const int i = r0 >> 8;
    const int bz = i >> 3, it = i & 7, t = it >> 2, j = it & 3;
    const int p0 = r0 & 255;
    const float* msk = ws + FMS + bz * 8 + t * 4;

    float4 a[8];
    #pragma unroll
    for (int r = 0; r < 8; ++r) a[r] = (float4){0.f, 0.f, 0.f, 0.f};

    #pragma unroll
    for (int cc = 0; cc < 4; ++cc){
      const float w = msk[cc];
      if (w != 0.f){
        const float* ep = E + (((size_t)((bz * 4 + cc) * 4 + j)) * 256 + p0) * DIM + d;
        #pragma unroll
        for (int r = 0; r < 8; ++r){
          const float4 v = *(const float4*)(ep + (size_t)r * DIM);
          a[r].x = fmaf(w, v.x, a[r].x);
          a[r].y = fmaf(w, v.y, a[r].y);
          a[r].z = fmaf(w, v.z, a[r].z);
          a[r].w = fmaf(w, v.w, a[r].w);
        }
      }
    }
    unsigned short* AI = (unsigned short*)ws + EAI;
    #pragma unroll
    for (int r = 0; r < 8; ++r){
      ushort4 h, l;
      h.x = f2h(a[r].x); l.x = f2h(a[r].x - h2f(h.x));
      h.y = f2h(a[r].y); l.y = f2h(a[r].y - h2f(h.y));
      h.z = f2h(a[r].z); l.z = f2h(a[r].z - h2f(h.z));
      h.w = f2h(a[r].w); l.w = f2h(a[r].w - h2f(h.w));
      const size_t base = (size_t)(r0 + r) * 2048 + kc * 64;
      *(ushort4*)&AI[base + c * 8 + pos]      = h;
      *(ushort4*)&AI[base + c * 8 + pos + 32] = l;
    }
  } else {
    const int r0 = (blk - 2048) * 8;   // 8 W rows
    unsigned short* WI = (unsigned short*)ws + EWI;
    float4 v[8];
    #pragma unroll
    for (int r = 0; r < 8; ++r)
      v[r] = *(const float4*)&W[(size_t)(r0 + r) * DIM + d];
    #pragma unroll
    for (int r = 0; r < 8; ++r){
      ushort4 h, l;
      h.x = f2h(v[r].x); l.x = f2h(v[r].x - h2f(h.x));
      h.y = f2h(v[r].y); l.y = f2h(v[r].y - h2f(h.y));
      h.z = f2h(v[r].z); l.z = f2h(v[r].z - h2f(h.z));
      h.w = f2h(v[r].w); l.w = f2h(v[r].w - h2f(h.w));
      const size_t base = (size_t)(r0 + r) * 2048 + kc * 64;
      *(ushort4*)&WI[base + c * 8 + pos]      = h;
      *(ushort4*)&WI[base + c * 8 + pos + 32] = l;
    }
  }
}

// ================= K4: split-fp16 MFMA GEMM, 256x256 tile, m-row pipeline ======
// Per kc: read B(8) + A-pairs 0,1 (4) up front (12 reads), then 8 MFMA row-blocks
// of 12; after row m, read A-pair m+2 into the freed register pair (2 named
// pairs alternate -> compile-time indices, rule #20). All reads past the first
// 12 are issued UNDER MFMA execution. sched_barrier(0) fences pin group order;
// the compiler's own counted lgkmcnt waits provide RAW ordering. End of kc:
// lgkmcnt(0)+vmcnt(0)+barrier (round-9 race rule).
__global__ __launch_bounds__(512) void k_gemm(const float* __restrict__ bk,
                                              float* __restrict__ ws)
{
  const unsigned short* AI = (const unsigned short*)ws + EAI;
  const unsigned short* WI = (const unsigned short*)ws + EWI;
  const float* gq = ws + FGQ;
  float* part = ws + FPART;

  __shared__ __align__(16) unsigned short Abuf[2][16384];  // 2 x 256 x 64
  __shared__ __align__(16) unsigned short Bbuf[2][16384];  // 2 x 256 x 64

  const int bid = blockIdx.x;                 // 0..255
  const int xcd = bid & 7, g = bid >> 3;      // g 0..31
  const int rt = xcd * 8 + (g >> 2);          // 0..63
  const int ct = g & 3;                       // 0..3
  const int R0 = rt * 256, C0 = ct * 256;
  const int tid = threadIdx.x;
  const int lane = tid & 63, wid = tid >> 6;
  const int wr = wid >> 2, wc = wid & 3;      // 2 x 4 wave grid
  const int b = R0 >> 11;

  const int src_off = (lane >> 3) * 2048 + (((lane & 7) ^ (lane >> 3)) << 3);
  const int pcH = ((lane >> 4) ^ (lane & 7)) * 16;
  const int pcL = pcH ^ 64;
  const int raw = wr * 128 + (lane & 15);     // A row base in tile
  const int rbw = wc * 64 + (lane & 15);      // B row base in tile

  f32x4 acc[8][4];
  #pragma unroll
  for (int m = 0; m < 8; ++m)
    #pragma unroll
    for (int n = 0; n < 4; ++n)
      acc[m][n] = (f32x4){0.f, 0.f, 0.f, 0.f};

  auto stageA = [&](int buf, int kc){
    const unsigned short* As = AI + (size_t)(R0 + wid * 32) * 2048 + kc * 64 + src_off;
    unsigned short* Ad = &Abuf[buf][wid * 2048];
    #pragma unroll
    for (int q = 0; q < 4; ++q) gl_lds16(As + (size_t)q * 8 * 2048, Ad + q * 512);
  };
  auto stageB = [&](int buf, int kc){
    const unsigned short* Bs = WI + (size_t)(C0 + wid * 32) * 2048 + kc * 64 + src_off;
    unsigned short* Bd = &Bbuf[buf][wid * 2048];
    #pragma unroll
    for (int q = 0; q < 4; ++q) gl_lds16(Bs + (size_t)q * 8 * 2048, Bd + q * 512);
  };

  stageA(0, 0);
  stageB(0, 0);
  asm volatile("s_waitcnt vmcnt(0)" ::: "memory");
  __builtin_amdgcn_s_barrier();

#define READ_PAIR(H, L, FM) do {                       \
    const int ro_ = (raw + (FM) * 16) << 7;            \
    (H) = *(const f16x8*)(pa + ro_ + pcH);             \
    (L) = *(const f16x8*)(pa + ro_ + pcL);             \
  } while (0)

#define MFMA_ROW(M, H, L) do {                                                           \
    __builtin_amdgcn_s_setprio(1);                                                       \
    _Pragma("unroll")                                                                    \
    for (int n = 0; n < 4; ++n){                                                         \
      acc[M][n] = __builtin_amdgcn_mfma_f32_16x16x32_f16((H), bh[n], acc[M][n], 0, 0, 0); \
      acc[M][n] = __builtin_amdgcn_mfma_f32_16x16x32_f16((H), bl[n], acc[M][n], 0, 0, 0); \
      acc[M][n] = __builtin_amdgcn_mfma_f32_16x16x32_f16((L), bh[n], acc[M][n], 0, 0, 0); \
    }                                                                                    \
    __builtin_amdgcn_s_setprio(0);                                                       \
    __builtin_amdgcn_sched_barrier(0);                                                   \
  } while (0)

  f16x8 aeh, ael, aoh, aol, bh[4], bl[4];

  #pragma unroll 1
  for (int kc = 0; kc < 32; ++kc){
    const int cur = kc & 1;
    const char* pa = (const char*)&Abuf[cur][0];
    const char* pb = (const char*)&Bbuf[cur][0];

    // upfront reads: B all (8) + A pairs 0,1 (4) = 12
    #pragma unroll
    for (int f = 0; f < 4; ++f){
      const int ro = (rbw + f * 16) << 7;
      bh[f] = *(const f16x8*)(pb + ro + pcH);
      bl[f] = *(const f16x8*)(pb + ro + pcL);
    }
    READ_PAIR(aeh, ael, 0);
    READ_PAIR(aoh, aol, 1);
    __builtin_amdgcn_sched_barrier(0);
    if (kc < 31){ stageA(cur ^ 1, kc + 1); stageB(cur ^ 1, kc + 1); }
    __builtin_amdgcn_sched_barrier(0);

    MFMA_ROW(0, aeh, ael);
    READ_PAIR(aeh, ael, 2);
    __builtin_amdgcn_sched_barrier(0);
    MFMA_ROW(1, aoh, aol);
    READ_PAIR(aoh, aol, 3);
    __builtin_amdgcn_sched_barrier(0);
    MFMA_ROW(2, aeh, ael);
    READ_PAIR(aeh, ael, 4);
    __builtin_amdgcn_sched_barrier(0);
    MFMA_ROW(3, aoh, aol);
    READ_PAIR(aoh, aol, 5);
    __builtin_amdgcn_sched_barrier(0);
    MFMA_ROW(4, aeh, ael);
    READ_PAIR(aeh, ael, 6);
    __builtin_amdgcn_sched_barrier(0);
    MFMA_ROW(5, aoh, aol);
    READ_PAIR(aoh, aol, 7);
    __builtin_amdgcn_sched_barrier(0);
    MFMA_ROW(6, aeh, ael);
    MFMA_ROW(7, aoh, aol);

    // end-of-kc fence: all this wave's LDS reads complete + stage writes landed
    asm volatile("s_waitcnt lgkmcnt(0)" ::: "memory");
    __builtin_amdgcn_sched_barrier(0);
    asm volatile("s_waitcnt vmcnt(0)" ::: "memory");
    __builtin_amdgcn_s_barrier();
  }
#undef READ_PAIR
#undef MFMA_ROW

  // epilogue: per-row stats (sum over this ct-tile's 256 cols)
  float bkv[4], gv[4];
  #pragma unroll
  for (int n = 0; n < 4; ++n){
    const int col = C0 + wc * 64 + n * 16 + (lane & 15);
    bkv[n] = bk[col];
    gv[n]  = gq[(size_t)b * DIM + col];
  }
  float* fred = (float*)&Abuf[0][0];   // 256*4*3 floats = 12KB, overlays Abuf
  #pragma unroll
  for (int m = 0; m < 8; ++m)
    #pragma unroll
    for (int r = 0; r < 4; ++r){
      float s = 0.f, q = 0.f, tv = 0.f;
      #pragma unroll
      for (int n = 0; n < 4; ++n){
        float y = acc[m][n][r] + bkv[n];
        s += y; q += y * y; tv += y * gv[n];
      }
      #pragma unroll
      for (int msk = 8; msk >= 1; msk >>= 1){
        s += __shfl_xor(s, msk); q += __shfl_xor(q, msk); tv += __shfl_xor(tv, msk);
      }
      if ((lane & 15) == 0){
        const int rl = wr * 128 + m * 16 + (lane >> 4) * 4 + r;
        fred[(rl * 4 + wc) * 3 + 0] = s;
        fred[(rl * 4 + wc) * 3 + 1] = q;
        fred[(rl * 4 + wc) * 3 + 2] = tv;
      }
    }
  __syncthreads();
  if (tid < 256){
    #pragma unroll
    for (int st = 0; st < 3; ++st){
      float v = fred[(tid * 4 + 0) * 3 + st] + fred[(tid * 4 + 1) * 3 + st]
              + fred[(tid * 4 + 2) * 3 + st] + fred[(tid * 4 + 3) * 3 + st];
      part[((size_t)ct * NROW + R0 + tid) * 3 + st] = v;
    }
  }
}

// ================= K5: probs2 (in-block) + reg gumbel + gather -> out ==========
__global__ __launch_bounds__(256) void k_out(const float* __restrict__ E,
                                             const float* __restrict__ ws,
                                             float* __restrict__ out)
{
  const int bid = blockIdx.x;
  const int i = bid >> 7, t2 = bid & 127;
  const int bz = i >> 3, it = i & 7, tt = it >> 2, j = it & 3;
  const int tid = threadIdx.x;
  __shared__ float red[4];
  __shared__ float wv[256];
  __shared__ float mloc[4];
  __shared__ unsigned long long mk[4];

  if (tid < 4) mloc[tid] = ws[FMS + bz * 8 + tt * 4 + tid];

  // --- probs2 recompute ---
  const float* part = ws + FPART;
  const int r = i * 256 + tid;
  float S = 0.f, Q = 0.f, T = 0.f;
  #pragma unroll
  for (int ct = 0; ct < NCT; ++ct){
    const float* pp = part + ((size_t)ct * NROW + r) * 3;
    S += pp[0]; Q += pp[1]; T += pp[2];
  }
  float mu  = S * (1.f / 1024.f);
  float var = Q * (1.f / 1024.f) - mu * mu;
  float sig = sqrtf(var + 1e-12f);
  float L = (T - mu * ws[FSG + bz]) / sig + ws[FCL + bz];
  float ML = blk_max(L, red);
  float wp2 = expf(L - ML);
  float swp = blk_sum(wp2, red);
  float p2 = wp2 / swp;

  // --- gumbel-softmax over 256 positions ---
  uint32_t k1a, k1b, k2a, k2b;
  jax_keys(k1a, k1b, k2a, k2b);
  const uint32_t fidx = ((uint32_t)(i * TOPJ + t2)) * 256u + (uint32_t)tid;
  float u = jax_uniform(k2a, k2b, fidx, 1048576u);
  float gmb = -logf(-logf(u));
  float x = (p2 + gmb) / 1e-6f;
  float M = blk_max(x, red);
  float w = expf(x - M);
  float sw = blk_sum(w, red);
  float wn = w / sw;
  wv[tid] = wn;
  unsigned long long bal = __ballot(wn != 0.f);
  if ((tid & 63) == 0) mk[tid >> 6] = bal;
  __syncthreads();

  const int d = tid << 2;
  float4 acc = {0.f, 0.f, 0.f, 0.f};
  for (int wq = 0; wq < 4; ++wq){
    unsigned long long mm = mk[wq];
    while (mm){
      const int l = __ffsll(mm) - 1;
      mm &= mm - 1;
      const int p = (wq << 6) + l;
      const float wpv = wv[p];
      #pragma unroll
      for (int c = 0; c < 4; ++c){
        const float mc = mloc[c];
        if (mc != 0.f){
          const float4 v = *(const float4*)&E[(((size_t)((bz * 4 + c) * 4 + j)) * 256 + p) * DIM + d];
          const float wm = wpv * mc;
          acc.x += wm * v.x; acc.y += wm * v.y; acc.z += wm * v.z; acc.w += wm * v.w;
        }
      }
    }
  }
  *(float4*)&out[((size_t)(i * TOPJ + t2)) * DIM + d] = acc;
}

// ---------------- launch ----------------
extern "C" void kernel_launch(void* const* d_in, const int* in_sizes, int n_in,
                              void* d_out, int out_size, void* d_ws, size_t ws_size,
                              hipStream_t stream)
{
  const float* qf    = (const float*)d_in[0];
  const float* E     = (const float*)d_in[1];
  const float* vcls  = (const float*)d_in[2];
  const float* sWq   = (const float*)d_in[3];
  const float* sbq   = (const float*)d_in[4];
  const float* slnqg = (const float*)d_in[5];
  const float* slnqb = (const float*)d_in[6];
  const float* sWk   = (const float*)d_in[7];
  const float* sbk   = (const float*)d_in[8];
  const float* slnkg = (const float*)d_in[9];
  const float* slnkb = (const float*)d_in[10];
  const float* rWq   = (const float*)d_in[11];
  const float* rbq   = (const float*)d_in[12];
  const float* rlnqg = (const float*)d_in[13];
  const float* rlnqb = (const float*)d_in[14];
  const float* rWk   = (const float*)d_in[15];
  const float* rbk   = (const float*)d_in[16];
  const float* rlnkg = (const float*)d_in[17];
  const float* rlnkb = (const float*)d_in[18];
  float* ws  = (float*)d_ws;
  float* out = (float*)d_out;

  k_matvec<<<256, 256, 0, stream>>>(qf, vcls, sWq, sbq, rWq, rbq, sWk, sbk, ws);
  k_post<<<BZ, 256, 0, stream>>>(slnqg, slnqb, rlnqg, rlnqb, rlnkg, rlnkb, slnkg, slnkb, ws);
  k_sel<<<2176, 256, 0, stream>>>(E, rWk, ws);
  k_gemm<<<256, 512, 0, stream>>>(rbk, ws);
  k_out<<<I2 * TOPJ, 256, 0, stream>>>(E, ws, out);
}

// Round 15
// 161.689 us; speedup vs baseline: 1.0456x; 1.0456x over previous
//
#include <hip/hip_runtime.h>
#include <hip/hip_fp16.h>
#include <stdint.h>

#ifndef JAX_PARTITIONABLE
#define JAX_PARTITIONABLE 1   // JAX >= 0.5 default threefry_partitionable
#endif

typedef _Float16 f16x8 __attribute__((ext_vector_type(8)));
typedef float    f32x4 __attribute__((ext_vector_type(4)));

// ---------------- problem sizes ----------------
static constexpr int BZ   = 8;
static constexpr int QD   = 512;
static constexpr int DIM  = 1024;
static constexpr int I2   = 64;
static constexpr int TOPJ = 128;
static constexpr int NROW = 16384;
static constexpr int NCT  = 4;      // 1024 / 256 col-tiles

// ---------------- ws layout ----------------
// ushort region, ROW-MAJOR interleaved:
//   AI[row][2048]: per row 32 kc-chunks x (32 hi | 32 lo) ushorts = 4KB/row
//   WI[row][2048]: same for the weight matrix
static constexpr size_t EAI = 0;                               // 16384*2048
static constexpr size_t EWI = (size_t)33554432;                // 1024*2048
// float region starts at float index 17,825,792
static constexpr size_t FQN   = 17825792;            // (unused, kept)
static constexpr size_t FSF   = FQN + 4096;          // (unused, kept)
static constexpr size_t FYS   = FSF + 32768;         // 8*1024
static constexpr size_t FYR   = FYS + 8192;          // 8*1024
static constexpr size_t FY2   = FYR + 8192;          // 8*4*1024
static constexpr size_t FGQ   = FY2 + 32768;         // 8*1024
static constexpr size_t FSG   = FGQ + 8192;          // 8
static constexpr size_t FCL   = FSG + 8;             // 8
static constexpr size_t FMS   = FCL + 8;             // 8*2*4
static constexpr size_t FP2   = FMS + 64;            // (unused, kept)
static constexpr size_t FPART = FP2 + 16384;         // NCT*16384*3

// ---------------- threefry2x32 (JAX-exact) ----------------
__device__ __forceinline__ uint32_t rotl32(uint32_t v, int d){ return (v << d) | (v >> (32 - d)); }

__device__ __forceinline__ void tf2x32(uint32_t k0, uint32_t k1, uint32_t x0, uint32_t x1,
                                       uint32_t& o0, uint32_t& o1){
  const uint32_t ks2 = k0 ^ k1 ^ 0x1BD11BDAu;
  x0 += k0; x1 += k1;
#define TFR(r) x0 += x1; x1 = rotl32(x1, r); x1 ^= x0;
  TFR(13) TFR(15) TFR(26) TFR(6)
  x0 += k1;  x1 += ks2 + 1u;
  TFR(17) TFR(29) TFR(16) TFR(24)
  x0 += ks2; x1 += k0 + 2u;
  TFR(13) TFR(15) TFR(26) TFR(6)
  x0 += k0;  x1 += k1 + 3u;
  TFR(17) TFR(29) TFR(16) TFR(24)
  x0 += k1;  x1 += ks2 + 4u;
  TFR(13) TFR(15) TFR(26) TFR(6)
  x0 += ks2; x1 += k0 + 5u;
#undef TFR
  o0 = x0; o1 = x1;
}

__device__ __forceinline__ void jax_keys(uint32_t& k1a, uint32_t& k1b, uint32_t& k2a, uint32_t& k2b){
#if JAX_PARTITIONABLE
  uint32_t a,b,c,d;
  tf2x32(0u, 42u, 0u, 0u, a, b);
  tf2x32(0u, 42u, 0u, 1u, c, d);
  k1a = a; k1b = b; k2a = c; k2b = d;
#else
  uint32_t a,b,c,d;
  tf2x32(0u, 42u, 0u, 2u, a, b);
  tf2x32(0u, 42u, 1u, 3u, c, d);
  k1a = a; k1b = c; k2a = b; k2b = d;
#endif
}

__device__ __forceinline__ float jax_uniform(uint32_t ka, uint32_t kb, uint32_t idx, uint32_t half_n){
  uint32_t o0, o1, bits;
#if JAX_PARTITIONABLE
  (void)half_n;
  tf2x32(ka, kb, 0u, idx, o0, o1);
  bits = o0 ^ o1;
#else
  if (idx < half_n){ tf2x32(ka, kb, idx, idx + half_n, o0, o1); bits = o0; }
  else             { tf2x32(ka, kb, idx - half_n, idx, o0, o1); bits = o1; }
#endif
  float f = __uint_as_float((bits >> 9) | 0x3f800000u) - 1.0f;
  f = f + 1e-20f;
  return fmaxf(f, 1e-20f);
}

// ---------------- block reductions (wave shuffle + 4-slot LDS, 2 barriers) ----
__device__ __forceinline__ float blk_sum(float v, float* red){
  __syncthreads();
  #pragma unroll
  for (int m = 32; m >= 1; m >>= 1) v += __shfl_xor(v, m);
  if ((threadIdx.x & 63) == 0) red[threadIdx.x >> 6] = v;
  __syncthreads();
  return red[0] + red[1] + red[2] + red[3];
}
__device__ __forceinline__ float blk_max(float v, float* red){
  __syncthreads();
  #pragma unroll
  for (int m = 32; m >= 1; m >>= 1) v = fmaxf(v, __shfl_xor(v, m));
  if ((threadIdx.x & 63) == 0) red[threadIdx.x >> 6] = v;
  __syncthreads();
  return fmaxf(fmaxf(red[0], red[1]), fmaxf(red[2], red[3]));
}

// ---------------- fp16 split helpers ----------------
__device__ __forceinline__ unsigned short f2h(float x){
  return __half_as_ushort(__float2half(x));
}
__device__ __forceinline__ float h2f(unsigned short u){
  return __half2float(__ushort_as_half(u));
}

// ---------------- async global->LDS (16B/lane) ----------------
__device__ __forceinline__ void gl_lds16(const void* g, void* l){
  __builtin_amdgcn_global_load_lds((const __attribute__((address_space(1))) void*)g,
                                   (__attribute__((address_space(3))) void*)l, 16, 0, 0);
}

// ================= K1: norms (in-block) + distributed matvecs =================
__global__ __launch_bounds__(256) void k_matvec(
    const float* __restrict__ qf, const float* __restrict__ vcls,
    const float* __restrict__ sWq, const float* __restrict__ sbq,
    const float* __restrict__ rWq, const float* __restrict__ rbq,
    const float* __restrict__ sWk, const float* __restrict__ sbk,
    float* __restrict__ ws)
{
  const int bid = blockIdx.x;
  const int b = bid >> 5, ch = bid & 31;
  const int tid = threadIdx.x;
  __shared__ float red[4];
  __shared__ float qn[QD];
  __shared__ float sf[4][DIM];

  // q-norm
  {
    float q0 = qf[b * QD + tid];
    float q1 = qf[b * QD + 256 + tid];
    float ss = blk_sum(q0*q0 + q1*q1, red);
    float nrm = sqrtf(ss);
    qn[tid] = q0 / nrm;
    qn[tid + 256] = q1 / nrm;
  }
  // seg_feat (mean of 4 L2-normalized frames per segment)
  {
    float sfr[4][4];
    #pragma unroll
    for (int c = 0; c < 4; ++c)
      #pragma unroll
      for (int r = 0; r < 4; ++r) sfr[c][r] = 0.f;
    for (int f = 0; f < 16; ++f){
      float v[4]; float s2 = 0.f;
      #pragma unroll
      for (int r = 0; r < 4; ++r){
        v[r] = vcls[((size_t)(b * 16 + f)) * DIM + tid + (r << 8)];
        s2 += v[r] * v[r];
      }
      float s = blk_sum(s2, red);
      float n2 = sqrtf(s);
      const int c = f >> 2;
      #pragma unroll
      for (int r = 0; r < 4; ++r) sfr[c][r] += v[r] / n2;
    }
    #pragma unroll
    for (int c = 0; c < 4; ++c)
      #pragma unroll
      for (int r = 0; r < 4; ++r)
        sf[c][tid + (r << 8)] = sfr[c][r] * 0.25f;
  }
  __syncthreads();

  const int di = tid >> 3, sub = tid & 7;
  const int d = ch * 32 + di;

  {
    const float* wr = sWq + (size_t)d * QD + sub * 64;
    const float* qq = qn + sub * 64;
    float a = 0.f;
    #pragma unroll
    for (int e = 0; e < 64; e += 4){
      float4 w4 = *(const float4*)(wr + e);
      a += qq[e]*w4.x + qq[e+1]*w4.y + qq[e+2]*w4.z + qq[e+3]*w4.w;
    }
    a += __shfl_xor(a, 1); a += __shfl_xor(a, 2); a += __shfl_xor(a, 4);
    if (sub == 0) ws[FYS + (size_t)b * DIM + d] = a + sbq[d];
  }
  {
    const float* wr = rWq + (size_t)d * QD + sub * 64;
    const float* qq = qn + sub * 64;
    float a = 0.f;
    #pragma unroll
    for (int e = 0; e < 64; e += 4){
      float4 w4 = *(const float4*)(wr + e);
      a += qq[e]*w4.x + qq[e+1]*w4.y + qq[e+2]*w4.z + qq[e+3]*w4.w;
    }
    a += __shfl_xor(a, 1); a += __shfl_xor(a, 2); a += __shfl_xor(a, 4);
    if (sub == 0) ws[FYR + (size_t)b * DIM + d] = a + rbq[d];
  }
  for (int c = 0; c < 4; ++c){
    const float* wr = sWk + (size_t)d * DIM + sub * 128;
    const float* qq = &sf[c][sub * 128];
    float a = 0.f;
    #pragma unroll
    for (int e = 0; e < 128; e += 4){
      float4 w4 = *(const float4*)(wr + e);
      a += qq[e]*w4.x + qq[e+1]*w4.y + qq[e+2]*w4.z + qq[e+3]*w4.w;
    }
    a += __shfl_xor(a, 1); a += __shfl_xor(a, 2); a += __shfl_xor(a, 4);
    if (sub == 0) ws[FY2 + ((size_t)(b * 4 + c)) * DIM + d] = a + sbk[d];
  }
}

// ================= K2: LN finishers + seg softmax/gumbel masks =================
__global__ __launch_bounds__(256) void k_post(
    const float* __restrict__ slnqg, const float* __restrict__ slnqb,
    const float* __restrict__ rlnqg, const float* __restrict__ rlnqb,
    const float* __restrict__ rlnkg, const float* __restrict__ rlnkb,
    const float* __restrict__ slnkg, const float* __restrict__ slnkb,
    float* __restrict__ ws)
{
  const int b = blockIdx.x, tid = threadIdx.x;
  __shared__ float red[4];
  __shared__ float qps[DIM];
  __shared__ float lg[4];

  {
    float y[4];
    #pragma unroll
    for (int r = 0; r < 4; ++r) y[r] = ws[FYS + (size_t)b * DIM + tid + (r << 8)];
    float S = blk_sum(y[0]+y[1]+y[2]+y[3], red);
    float mu = S * (1.f / 1024.f);
    float pv = 0.f;
    #pragma unroll
    for (int r = 0; r < 4; ++r){ float dv = y[r]-mu; pv += dv*dv; }
    float V = blk_sum(pv, red);
    float sig = sqrtf(V * (1.f / 1024.f) + 1e-12f);
    #pragma unroll
    for (int r = 0; r < 4; ++r){
      const int d = tid + (r << 8);
      qps[d] = (y[r]-mu)/sig * slnqg[d] + slnqb[d];
    }
  }
  __syncthreads();

  {
    float y[4];
    #pragma unroll
    for (int r = 0; r < 4; ++r) y[r] = ws[FYR + (size_t)b * DIM + tid + (r << 8)];
    float S = blk_sum(y[0]+y[1]+y[2]+y[3], red);
    float mu = S * (1.f / 1024.f);
    float pv = 0.f;
    #pragma unroll
    for (int r = 0; r < 4; ++r){ float dv = y[r]-mu; pv += dv*dv; }
    float V = blk_sum(pv, red);
    float sig = sqrtf(V * (1.f / 1024.f) + 1e-12f);
    float sg = 0.f, cl = 0.f;
    #pragma unroll
    for (int r = 0; r < 4; ++r){
      const int d = tid + (r << 8);
      float o = (y[r]-mu)/sig * rlnqg[d] + rlnqb[d];
      float gv = rlnkg[d] * o;
      ws[FGQ + (size_t)b * DIM + d] = gv;
      sg += gv;
      cl += rlnkb[d] * o;
    }
    float SG = blk_sum(sg, red);
    float CL = blk_sum(cl, red);
    if (tid == 0){ ws[FSG + b] = SG; ws[FCL + b] = CL; }
  }

  for (int c = 0; c < 4; ++c){
    float y[4];
    #pragma unroll
    for (int r = 0; r < 4; ++r) y[r] = ws[FY2 + ((size_t)(b * 4 + c)) * DIM + tid + (r << 8)];
    float S = blk_sum(y[0]+y[1]+y[2]+y[3], red);
    float mu = S * (1.f / 1024.f);
    float pv = 0.f;
    #pragma unroll
    for (int r = 0; r < 4; ++r){ float dv = y[r]-mu; pv += dv*dv; }
    float V = blk_sum(pv, red);
    float sig = sqrtf(V * (1.f / 1024.f) + 1e-12f);
    float lp = 0.f;
    #pragma unroll
    for (int r = 0; r < 4; ++r){
      const int d = tid + (r << 8);
      float kp = (y[r]-mu)/sig * slnkg[d] + slnkb[d];
      lp += kp * qps[d];
    }
    float L = blk_sum(lp, red);
    if (tid == 0) lg[c] = L;
  }
  __syncthreads();

  if (tid == 0){
    float m = fmaxf(fmaxf(lg[0], lg[1]), fmaxf(lg[2], lg[3]));
    float e[4], s = 0.f;
    #pragma unroll
    for (int c = 0; c < 4; ++c){ e[c] = expf(lg[c] - m); s += e[c]; }
    float probs[4];
    #pragma unroll
    for (int c = 0; c < 4; ++c) probs[c] = e[c] / s;
    uint32_t k1a, k1b, k2a, k2b;
    jax_keys(k1a, k1b, k2a, k2b);
    for (int t = 0; t < 2; ++t){
      float x[4];
      #pragma unroll
      for (int c = 0; c < 4; ++c){
        float u = jax_uniform(k1a, k1b, (uint32_t)(b * 8 + t * 4 + c), 32u);
        float gmb = -logf(-logf(u));
        x[c] = (probs[c] + gmb) / 1e-6f;
      }
      float xm = fmaxf(fmaxf(x[0], x[1]), fmaxf(x[2], x[3]));
      float w[4], sw = 0.f;
      #pragma unroll
      for (int c = 0; c < 4; ++c){ w[c] = expf(x[c] - xm); sw += w[c]; }
      #pragma unroll
      for (int c = 0; c < 4; ++c) ws[FMS + b * 8 + t * 4 + c] = w[c] / sw;
    }
  }
}

// ================= K3: sel rows -> AI; tail: W -> WI (8 rows/block, fat) =======
__global__ __launch_bounds__(256) void k_sel(const float* __restrict__ E,
                                             const float* __restrict__ W,
                                             float* __restrict__ ws)
{
  const int blk = blockIdx.x;
  const int th = threadIdx.x;
  const int kc = th >> 3;              // 0..31
  const int c  = (th & 7) >> 1;        // 16B chunk within 32-elem half
  const int pos = (th & 1) * 4;
  const int d = th << 2;

  if (blk < 2048){
    const int r0 = blk * 8;            // 8 rows, all in pseudo-batch i
    const int i = r0 >> 8;
    const int bz = i >> 3, it = i & 7, t = it >> 2, j = it & 3;
    const int p0 = r0 & 255;
    const float* msk = ws + FMS + bz * 8 + t * 4;

    float4 a[8];
    #pragma unroll
    for (int r = 0; r < 8; ++r) a[r] = (float4){0.f, 0.f, 0.f, 0.f};

    #pragma unroll
    for (int cc = 0; cc < 4; ++cc){
      const float w = msk[cc];
      if (w != 0.f){
        const float* ep = E + (((size_t)((bz * 4 + cc) * 4 + j)) * 256 + p0) * DIM + d;
        #pragma unroll
        for (int r = 0; r < 8; ++r){
          const float4 v = *(const float4*)(ep + (size_t)r * DIM);
          a[r].x = fmaf(w, v.x, a[r].x);
          a[r].y = fmaf(w, v.y, a[r].y);
          a[r].z = fmaf(w, v.z, a[r].z);
          a[r].w = fmaf(w, v.w, a[r].w);
        }
      }
    }
    unsigned short* AI = (unsigned short*)ws + EAI;
    #pragma unroll
    for (int r = 0; r < 8; ++r){
      ushort4 h, l;
      h.x = f2h(a[r].x); l.x = f2h(a[r].x - h2f(h.x));
      h.y = f2h(a[r].y); l.y = f2h(a[r].y - h2f(h.y));
      h.z = f2h(a[r].z); l.z = f2h(a[r].z - h2f(h.z));
      h.w = f2h(a[r].w); l.w = f2h(a[r].w - h2f(h.w));
      const size_t base = (size_t)(r0 + r) * 2048 + kc * 64;
      *(ushort4*)&AI[base + c * 8 + pos]      = h;
      *(ushort4*)&AI[base + c * 8 + pos + 32] = l;
    }
  } else {
    const int r0 = (blk - 2048) * 8;   // 8 W rows
    unsigned short* WI = (unsigned short*)ws + EWI;
    float4 v[8];
    #pragma unroll
    for (int r = 0; r < 8; ++r)
      v[r] = *(const float4*)&W[(size_t)(r0 + r) * DIM + d];
    #pragma unroll
    for (int r = 0; r < 8; ++r){
      ushort4 h, l;
      h.x = f2h(v[r].x); l.x = f2h(v[r].x - h2f(h.x));
      h.y = f2h(v[r].y); l.y = f2h(v[r].y - h2f(h.y));
      h.z = f2h(v[r].z); l.z = f2h(v[r].z - h2f(h.z));
      h.w = f2h(v[r].w); l.w = f2h(v[r].w - h2f(h.w));
      const size_t base = (size_t)(r0 + r) * 2048 + kc * 64;
      *(ushort4*)&WI[base + c * 8 + pos]      = h;
      *(ushort4*)&WI[base + c * 8 + pos + 32] = l;
    }
  }
}

// ================= K4: split-fp16 MFMA GEMM, 256x256 tile, drift-phases ========
// Round-13 schedule (best measured: 84us, MfmaUtil 54%) — restored verbatim.
// Per-phase lgkmcnt(0)+sched_barrier pins + setprio, NO mid-kc barriers (waves
// drift); single end-of-kc lgkmcnt(0)+vmcnt(0)+barrier (round-9 race rule).
__global__ __launch_bounds__(512) void k_gemm(const float* __restrict__ bk,
                                              float* __restrict__ ws)
{
  const unsigned short* AI = (const unsigned short*)ws + EAI;
  const unsigned short* WI = (const unsigned short*)ws + EWI;
  const float* gq = ws + FGQ;
  float* part = ws + FPART;

  __shared__ __align__(16) unsigned short Abuf[2][16384];  // 2 x 256 x 64
  __shared__ __align__(16) unsigned short Bbuf[2][16384];  // 2 x 256 x 64

  const int bid = blockIdx.x;                 // 0..255
  const int xcd = bid & 7, g = bid >> 3;      // g 0..31
  const int rt = xcd * 8 + (g >> 2);          // 0..63
  const int ct = g & 3;                       // 0..3
  const int R0 = rt * 256, C0 = ct * 256;
  const int tid = threadIdx.x;
  const int lane = tid & 63, wid = tid >> 6;
  const int wr = wid >> 2, wc = wid & 3;      // 2 x 4 wave grid
  const int b = R0 >> 11;

  const int src_off = (lane >> 3) * 2048 + (((lane & 7) ^ (lane >> 3)) << 3);
  const int pcH = ((lane >> 4) ^ (lane & 7)) * 16;
  const int pcL = pcH ^ 64;
  const int raw = wr * 128 + (lane & 15);     // A row base in tile
  const int rbw = wc * 64 + (lane & 15);      // B row base in tile

  f32x4 acc[8][4];
  #pragma unroll
  for (int m = 0; m < 8; ++m)
    #pragma unroll
    for (int n = 0; n < 4; ++n)
      acc[m][n] = (f32x4){0.f, 0.f, 0.f, 0.f};

  auto stageA = [&](int buf, int kc){
    const unsigned short* As = AI + (size_t)(R0 + wid * 32) * 2048 + kc * 64 + src_off;
    unsigned short* Ad = &Abuf[buf][wid * 2048];
    #pragma unroll
    for (int q = 0; q < 4; ++q) gl_lds16(As + (size_t)q * 8 * 2048, Ad + q * 512);
  };
  auto stageB = [&](int buf, int kc){
    const unsigned short* Bs = WI + (size_t)(C0 + wid * 32) * 2048 + kc * 64 + src_off;
    unsigned short* Bd = &Bbuf[buf][wid * 2048];
    #pragma unroll
    for (int q = 0; q < 4; ++q) gl_lds16(Bs + (size_t)q * 8 * 2048, Bd + q * 512);
  };

  stageA(0, 0);
  stageB(0, 0);
  asm volatile("s_waitcnt vmcnt(0)" ::: "memory");
  __builtin_amdgcn_s_barrier();

  f16x8 ah[4], al[4], bh[4], bl[4];

  #pragma unroll 1
  for (int kc = 0; kc < 32; ++kc){
    const int cur = kc & 1;
    const char* pa = (const char*)&Abuf[cur][0];
    const char* pb = (const char*)&Bbuf[cur][0];

    // ---- phase 0: A fm0-3 + B fn0-1 reads; stage A(kc+1); MFMA (m0-3, n0-1)
    #pragma unroll
    for (int f = 0; f < 4; ++f){
      const int ro = (raw + f * 16) << 7;
      ah[f] = *(const f16x8*)(pa + ro + pcH);
      al[f] = *(const f16x8*)(pa + ro + pcL);
    }
    #pragma unroll
    for (int f = 0; f < 2; ++f){
      const int ro = (rbw + f * 16) << 7;
      bh[f] = *(const f16x8*)(pb + ro + pcH);
      bl[f] = *(const f16x8*)(pb + ro + pcL);
    }
    if (kc < 31) stageA(cur ^ 1, kc + 1);
    asm volatile("s_waitcnt lgkmcnt(0)" ::: "memory");
    __builtin_amdgcn_sched_barrier(0);
    __builtin_amdgcn_s_setprio(1);
    #pragma unroll
    for (int m = 0; m < 4; ++m)
      #pragma unroll
      for (int n = 0; n < 2; ++n){
        acc[m][n] = __builtin_amdgcn_mfma_f32_16x16x32_f16(ah[m], bh[n], acc[m][n], 0, 0, 0);
        acc[m][n] = __builtin_amdgcn_mfma_f32_16x16x32_f16(ah[m], bl[n], acc[m][n], 0, 0, 0);
        acc[m][n] = __builtin_amdgcn_mfma_f32_16x16x32_f16(al[m], bh[n], acc[m][n], 0, 0, 0);
      }
    __builtin_amdgcn_s_setprio(0);

    // ---- phase 1: B fn2-3 reads; stage B(kc+1); MFMA (m0-3, n2-3)
    #pragma unroll
    for (int f = 2; f < 4; ++f){
      const int ro = (rbw + f * 16) << 7;
      bh[f] = *(const f16x8*)(pb + ro + pcH);
      bl[f] = *(const f16x8*)(pb + ro + pcL);
    }
    if (kc < 31) stageB(cur ^ 1, kc + 1);
    asm volatile("s_waitcnt lgkmcnt(0)" ::: "memory");
    __builtin_amdgcn_sched_barrier(0);
    __builtin_amdgcn_s_setprio(1);
    #pragma unroll
    for (int m = 0; m < 4; ++m)
      #pragma unroll
      for (int n = 2; n < 4; ++n){
        acc[m][n] = __builtin_amdgcn_mfma_f32_16x16x32_f16(ah[m], bh[n], acc[m][n], 0, 0, 0);
        acc[m][n] = __builtin_amdgcn_mfma_f32_16x16x32_f16(ah[m], bl[n], acc[m][n], 0, 0, 0);
        acc[m][n] = __builtin_amdgcn_mfma_f32_16x16x32_f16(al[m], bh[n], acc[m][n], 0, 0, 0);
      }
    __builtin_amdgcn_s_setprio(0);

    // ---- phase 2: A fm4-7 reads (overwrite ah/al); MFMA (m4-7, n0-1)
    #pragma unroll
    for (int f = 0; f < 4; ++f){
      const int ro = (raw + 64 + f * 16) << 7;
      ah[f] = *(const f16x8*)(pa + ro + pcH);
      al[f] = *(const f16x8*)(pa + ro + pcL);
    }
    asm volatile("s_waitcnt lgkmcnt(0)" ::: "memory");
    __builtin_amdgcn_sched_barrier(0);
    __builtin_amdgcn_s_setprio(1);
    #pragma unroll
    for (int m = 0; m < 4; ++m)
      #pragma unroll
      for (int n = 0; n < 2; ++n){
        acc[m + 4][n] = __builtin_amdgcn_mfma_f32_16x16x32_f16(ah[m], bh[n], acc[m + 4][n], 0, 0, 0);
        acc[m + 4][n] = __builtin_amdgcn_mfma_f32_16x16x32_f16(ah[m], bl[n], acc[m + 4][n], 0, 0, 0);
        acc[m + 4][n] = __builtin_amdgcn_mfma_f32_16x16x32_f16(al[m], bh[n], acc[m + 4][n], 0, 0, 0);
      }
    __builtin_amdgcn_s_setprio(0);

    // ---- phase 3: MFMA (m4-7, n2-3); kc-end drain + ONE barrier
    __builtin_amdgcn_s_setprio(1);
    #pragma unroll
    for (int m = 0; m < 4; ++m)
      #pragma unroll
      for (int n = 2; n < 4; ++n){
        acc[m + 4][n] = __builtin_amdgcn_mfma_f32_16x16x32_f16(ah[m], bh[n], acc[m + 4][n], 0, 0, 0);
        acc[m + 4][n] = __builtin_amdgcn_mfma_f32_16x16x32_f16(ah[m], bl[n], acc[m + 4][n], 0, 0, 0);
        acc[m + 4][n] = __builtin_amdgcn_mfma_f32_16x16x32_f16(al[m], bh[n], acc[m + 4][n], 0, 0, 0);
      }
    __builtin_amdgcn_s_setprio(0);
    asm volatile("s_waitcnt lgkmcnt(0)" ::: "memory");  // all this wave's LDS reads done
    __builtin_amdgcn_sched_barrier(0);
    asm volatile("s_waitcnt vmcnt(0)" ::: "memory");    // kc+1 stages landed
    __builtin_amdgcn_s_barrier();
  }

  // epilogue: per-row stats (sum over this ct-tile's 256 cols)
  float bkv[4], gv[4];
  #pragma unroll
  for (int n = 0; n < 4; ++n){
    const int col = C0 + wc * 64 + n * 16 + (lane & 15);
    bkv[n] = bk[col];
    gv[n]  = gq[(size_t)b * DIM + col];
  }
  float* fred = (float*)&Abuf[0][0];   // 256*4*3 floats = 12KB, overlays Abuf
  #pragma unroll
  for (int m = 0; m < 8; ++m)
    #pragma unroll
    for (int r = 0; r < 4; ++r){
      float s = 0.f, q = 0.f, tv = 0.f;
      #pragma unroll
      for (int n = 0; n < 4; ++n){
        float y = acc[m][n][r] + bkv[n];
        s += y; q += y * y; tv += y * gv[n];
      }
      #pragma unroll
      for (int msk = 8; msk >= 1; msk >>= 1){
        s += __shfl_xor(s, msk); q += __shfl_xor(q, msk); tv += __shfl_xor(tv, msk);
      }
      if ((lane & 15) == 0){
        const int rl = wr * 128 + m * 16 + (lane >> 4) * 4 + r;
        fred[(rl * 4 + wc) * 3 + 0] = s;
        fred[(rl * 4 + wc) * 3 + 1] = q;
        fred[(rl * 4 + wc) * 3 + 2] = tv;
      }
    }
  __syncthreads();
  if (tid < 256){
    #pragma unroll
    for (int st = 0; st < 3; ++st){
      float v = fred[(tid * 4 + 0) * 3 + st] + fred[(tid * 4 + 1) * 3 + st]
              + fred[(tid * 4 + 2) * 3 + st] + fred[(tid * 4 + 3) * 3 + st];
      part[((size_t)ct * NROW + R0 + tid) * 3 + st] = v;
    }
  }
}

// ================= K5: probs2 (once) + 4x (gumbel + gather) -> out =============
// Fattened: one block handles 4 consecutive t2 of one i (grid 8192 -> 2048),
// computing the probs2 softmax ONCE and amortizing part[] reads + launch
// overhead 4x. wv/mk reuse across sub-iterations is fenced by the reductions'
// entry barriers.
__global__ __launch_bounds__(256) void k_out(const float* __restrict__ E,
                                             const float* __restrict__ ws,
                                             float* __restrict__ out)
{
  const int bid = blockIdx.x;           // 0..2047
  const int i = bid >> 5, tg = (bid & 31) << 2;   // t2 in [tg, tg+4)
  const int bz = i >> 3, it = i & 7, tt = it >> 2, j = it & 3;
  const int tid = threadIdx.x;
  __shared__ float red[4];
  __shared__ float wv[256];
  __shared__ float mloc[4];
  __shared__ unsigned long long mk[4];

  if (tid < 4) mloc[tid] = ws[FMS + bz * 8 + tt * 4 + tid];

  // --- probs2 recompute (once per block) ---
  const float* part = ws + FPART;
  const int r = i * 256 + tid;
  float S = 0.f, Q = 0.f, T = 0.f;
  #pragma unroll
  for (int ct = 0; ct < NCT; ++ct){
    const float* pp = part + ((size_t)ct * NROW + r) * 3;
    S += pp[0]; Q += pp[1]; T += pp[2];
  }
  float mu  = S * (1.f / 1024.f);
  float var = Q * (1.f / 1024.f) - mu * mu;
  float sig = sqrtf(var + 1e-12f);
  float L = (T - mu * ws[FSG + bz]) / sig + ws[FCL + bz];
  float ML = blk_max(L, red);
  float wp2 = expf(L - ML);
  float swp = blk_sum(wp2, red);
  float p2 = wp2 / swp;

  uint32_t k1a, k1b, k2a, k2b;
  jax_keys(k1a, k1b, k2a, k2b);
  const int d = tid << 2;

  #pragma unroll 1
  for (int s = 0; s < 4; ++s){
    const int t2 = tg + s;
    const uint32_t fidx = ((uint32_t)(i * TOPJ + t2)) * 256u + (uint32_t)tid;
    float u = jax_uniform(k2a, k2b, fidx, 1048576u);
    float gmb = -logf(-logf(u));
    float x = (p2 + gmb) / 1e-6f;
    float M = blk_max(x, red);           // entry barrier also fences wv reuse
    float w = expf(x - M);
    float sw = blk_sum(w, red);
    float wn = w / sw;
    wv[tid] = wn;
    unsigned long long bal = __ballot(wn != 0.f);
    if ((tid & 63) == 0) mk[tid >> 6] = bal;
    __syncthreads();

    float4 acc = {0.f, 0.f, 0.f, 0.f};
    for (int wq = 0; wq < 4; ++wq){
      unsigned long long mm = mk[wq];
      while (mm){
        const int l = __ffsll(mm) - 1;
        mm &= mm - 1;
        const int p = (wq << 6) + l;
        const float wpv = wv[p];
        #pragma unroll
        for (int c = 0; c < 4; ++c){
          const float mc = mloc[c];
          if (mc != 0.f){
            const float4 v = *(const float4*)&E[(((size_t)((bz * 4 + c) * 4 + j)) * 256 + p) * DIM + d];
            const float wm = wpv * mc;
            acc.x += wm * v.x; acc.y += wm * v.y; acc.z += wm * v.z; acc.w += wm * v.w;
          }
        }
      }
    }
    *(float4*)&out[((size_t)(i * TOPJ + t2)) * DIM + d] = acc;
  }
}

// ---------------- launch ----------------
extern "C" void kernel_launch(void* const* d_in, const int* in_sizes, int n_in,
                              void* d_out, int out_size, void* d_ws, size_t ws_size,
                              hipStream_t stream)
{
  const float* qf    = (const float*)d_in[0];
  const float* E     = (const float*)d_in[1];
  const float* vcls  = (const float*)d_in[2];
  const float* sWq   = (const float*)d_in[3];
  const float* sbq   = (const float*)d_in[4];
  const float* slnqg = (const float*)d_in[5];
  const float* slnqb = (const float*)d_in[6];
  const float* sWk   = (const float*)d_in[7];
  const float* sbk   = (const float*)d_in[8];
  const float* slnkg = (const float*)d_in[9];
  const float* slnkb = (const float*)d_in[10];
  const float* rWq   = (const float*)d_in[11];
  const float* rbq   = (const float*)d_in[12];
  const float* rlnqg = (const float*)d_in[13];
  const float* rlnqb = (const float*)d_in[14];
  const float* rWk   = (const float*)d_in[15];
  const float* rbk   = (const float*)d_in[16];
  const float* rlnkg = (const float*)d_in[17];
  const float* rlnkb = (const float*)d_in[18];
  float* ws  = (float*)d_ws;
  float* out = (float*)d_out;

  k_matvec<<<256, 256, 0, stream>>>(qf, vcls, sWq, sbq, rWq, rbq, sWk, sbk, ws);
  k_post<<<BZ, 256, 0, stream>>>(slnqg, slnqb, rlnqg, rlnqb, rlnkg, rlnkb, slnkg, slnkb, ws);
  k_sel<<<2176, 256, 0, stream>>>(E, rWk, ws);
  k_gemm<<<256, 512, 0, stream>>>(rbk, ws);
  k_out<<<2048, 256, 0, stream>>>(E, ws, out);
}

// Round 16
// 160.742 us; speedup vs baseline: 1.0517x; 1.0059x over previous
//
#include <hip/hip_runtime.h>
#include <hip/hip_fp16.h>
#include <stdint.h>

#ifndef JAX_PARTITIONABLE
#define JAX_PARTITIONABLE 1   // JAX >= 0.5 default threefry_partitionable
#endif

typedef _Float16 f16x8 __attribute__((ext_vector_type(8)));
typedef float    f32x4 __attribute__((ext_vector_type(4)));

// ---------------- problem sizes ----------------
static constexpr int BZ   = 8;
static constexpr int QD   = 512;
static constexpr int DIM  = 1024;
static constexpr int I2   = 64;
static constexpr int TOPJ = 128;
static constexpr int NROW = 16384;
static constexpr int NCT  = 4;      // 1024 / 256 col-tiles

// ---------------- ws layout ----------------
// ushort region, ROW-MAJOR interleaved:
//   AI[row][2048]: per row 32 kc-chunks x (32 hi | 32 lo) ushorts = 4KB/row
//   WI[row][2048]: same for the weight matrix
static constexpr size_t EAI = 0;                               // 16384*2048
static constexpr size_t EWI = (size_t)33554432;                // 1024*2048
// float region starts at float index 17,825,792
static constexpr size_t FQN   = 17825792;            // (unused, kept)
static constexpr size_t FSF   = FQN + 4096;          // (unused, kept)
static constexpr size_t FYS   = FSF + 32768;         // 8*1024
static constexpr size_t FYR   = FYS + 8192;          // 8*1024
static constexpr size_t FY2   = FYR + 8192;          // 8*4*1024
static constexpr size_t FGQ   = FY2 + 32768;         // 8*1024
static constexpr size_t FSG   = FGQ + 8192;          // 8
static constexpr size_t FCL   = FSG + 8;             // 8
static constexpr size_t FMS   = FCL + 8;             // 8*2*4
static constexpr size_t FP2   = FMS + 64;            // (unused, kept)
static constexpr size_t FPART = FP2 + 16384;         // NCT*16384*3

// ---------------- threefry2x32 (JAX-exact) ----------------
__device__ __forceinline__ uint32_t rotl32(uint32_t v, int d){ return (v << d) | (v >> (32 - d)); }

__device__ __forceinline__ void tf2x32(uint32_t k0, uint32_t k1, uint32_t x0, uint32_t x1,
                                       uint32_t& o0, uint32_t& o1){
  const uint32_t ks2 = k0 ^ k1 ^ 0x1BD11BDAu;
  x0 += k0; x1 += k1;
#define TFR(r) x0 += x1; x1 = rotl32(x1, r); x1 ^= x0;
  TFR(13) TFR(15) TFR(26) TFR(6)
  x0 += k1;  x1 += ks2 + 1u;
  TFR(17) TFR(29) TFR(16) TFR(24)
  x0 += ks2; x1 += k0 + 2u;
  TFR(13) TFR(15) TFR(26) TFR(6)
  x0 += k0;  x1 += k1 + 3u;
  TFR(17) TFR(29) TFR(16) TFR(24)
  x0 += k1;  x1 += ks2 + 4u;
  TFR(13) TFR(15) TFR(26) TFR(6)
  x0 += ks2; x1 += k0 + 5u;
#undef TFR
  o0 = x0; o1 = x1;
}

__device__ __forceinline__ void jax_keys(uint32_t& k1a, uint32_t& k1b, uint32_t& k2a, uint32_t& k2b){
#if JAX_PARTITIONABLE
  uint32_t a,b,c,d;
  tf2x32(0u, 42u, 0u, 0u, a, b);
  tf2x32(0u, 42u, 0u, 1u, c, d);
  k1a = a; k1b = b; k2a = c; k2b = d;
#else
  uint32_t a,b,c,d;
  tf2x32(0u, 42u, 0u, 2u, a, b);
  tf2x32(0u, 42u, 1u, 3u, c, d);
  k1a = a; k1b = c; k2a = b; k2b = d;
#endif
}

__device__ __forceinline__ float jax_uniform(uint32_t ka, uint32_t kb, uint32_t idx, uint32_t half_n){
  uint32_t o0, o1, bits;
#if JAX_PARTITIONABLE
  (void)half_n;
  tf2x32(ka, kb, 0u, idx, o0, o1);
  bits = o0 ^ o1;
#else
  if (idx < half_n){ tf2x32(ka, kb, idx, idx + half_n, o0, o1); bits = o0; }
  else             { tf2x32(ka, kb, idx - half_n, idx, o0, o1); bits = o1; }
#endif
  float f = __uint_as_float((bits >> 9) | 0x3f800000u) - 1.0f;
  f = f + 1e-20f;
  return fmaxf(f, 1e-20f);
}

// ---------------- block reductions (wave shuffle + 4-slot LDS, 2 barriers) ----
__device__ __forceinline__ float blk_sum(float v, float* red){
  __syncthreads();
  #pragma unroll
  for (int m = 32; m >= 1; m >>= 1) v += __shfl_xor(v, m);
  if ((threadIdx.x & 63) == 0) red[threadIdx.x >> 6] = v;
  __syncthreads();
  return red[0] + red[1] + red[2] + red[3];
}
__device__ __forceinline__ float blk_max(float v, float* red){
  __syncthreads();
  #pragma unroll
  for (int m = 32; m >= 1; m >>= 1) v = fmaxf(v, __shfl_xor(v, m));
  if ((threadIdx.x & 63) == 0) red[threadIdx.x >> 6] = v;
  __syncthreads();
  return fmaxf(fmaxf(red[0], red[1]), fmaxf(red[2], red[3]));
}

// ---------------- fp16 split helpers ----------------
__device__ __forceinline__ unsigned short f2h(float x){
  return __half_as_ushort(__float2half(x));
}
__device__ __forceinline__ float h2f(unsigned short u){
  return __half2float(__ushort_as_half(u));
}

// ---------------- async global->LDS (16B/lane) ----------------
__device__ __forceinline__ void gl_lds16(const void* g, void* l){
  __builtin_amdgcn_global_load_lds((const __attribute__((address_space(1))) void*)g,
                                   (__attribute__((address_space(3))) void*)l, 16, 0, 0);
}

// ================= K1: norms (in-block) + distributed matvecs =================
__global__ __launch_bounds__(256) void k_matvec(
    const float* __restrict__ qf, const float* __restrict__ vcls,
    const float* __restrict__ sWq, const float* __restrict__ sbq,
    const float* __restrict__ rWq, const float* __restrict__ rbq,
    const float* __restrict__ sWk, const float* __restrict__ sbk,
    float* __restrict__ ws)
{
  const int bid = blockIdx.x;
  const int b = bid >> 5, ch = bid & 31;
  const int tid = threadIdx.x;
  __shared__ float red[4];
  __shared__ float qn[QD];
  __shared__ float sf[4][DIM];

  // q-norm
  {
    float q0 = qf[b * QD + tid];
    float q1 = qf[b * QD + 256 + tid];
    float ss = blk_sum(q0*q0 + q1*q1, red);
    float nrm = sqrtf(ss);
    qn[tid] = q0 / nrm;
    qn[tid + 256] = q1 / nrm;
  }
  // seg_feat (mean of 4 L2-normalized frames per segment)
  {
    float sfr[4][4];
    #pragma unroll
    for (int c = 0; c < 4; ++c)
      #pragma unroll
      for (int r = 0; r < 4; ++r) sfr[c][r] = 0.f;
    for (int f = 0; f < 16; ++f){
      float v[4]; float s2 = 0.f;
      #pragma unroll
      for (int r = 0; r < 4; ++r){
        v[r] = vcls[((size_t)(b * 16 + f)) * DIM + tid + (r << 8)];
        s2 += v[r] * v[r];
      }
      float s = blk_sum(s2, red);
      float n2 = sqrtf(s);
      const int c = f >> 2;
      #pragma unroll
      for (int r = 0; r < 4; ++r) sfr[c][r] += v[r] / n2;
    }
    #pragma unroll
    for (int c = 0; c < 4; ++c)
      #pragma unroll
      for (int r = 0; r < 4; ++r)
        sf[c][tid + (r << 8)] = sfr[c][r] * 0.25f;
  }
  __syncthreads();

  const int di = tid >> 3, sub = tid & 7;
  const int d = ch * 32 + di;

  {
    const float* wr = sWq + (size_t)d * QD + sub * 64;
    const float* qq = qn + sub * 64;
    float a = 0.f;
    #pragma unroll
    for (int e = 0; e < 64; e += 4){
      float4 w4 = *(const float4*)(wr + e);
      a += qq[e]*w4.x + qq[e+1]*w4.y + qq[e+2]*w4.z + qq[e+3]*w4.w;
    }
    a += __shfl_xor(a, 1); a += __shfl_xor(a, 2); a += __shfl_xor(a, 4);
    if (sub == 0) ws[FYS + (size_t)b * DIM + d] = a + sbq[d];
  }
  {
    const float* wr = rWq + (size_t)d * QD + sub * 64;
    const float* qq = qn + sub * 64;
    float a = 0.f;
    #pragma unroll
    for (int e = 0; e < 64; e += 4){
      float4 w4 = *(const float4*)(wr + e);
      a += qq[e]*w4.x + qq[e+1]*w4.y + qq[e+2]*w4.z + qq[e+3]*w4.w;
    }
    a += __shfl_xor(a, 1); a += __shfl_xor(a, 2); a += __shfl_xor(a, 4);
    if (sub == 0) ws[FYR + (size_t)b * DIM + d] = a + rbq[d];
  }
  for (int c = 0; c < 4; ++c){
    const float* wr = sWk + (size_t)d * DIM + sub * 128;
    const float* qq = &sf[c][sub * 128];
    float a = 0.f;
    #pragma unroll
    for (int e = 0; e < 128; e += 4){
      float4 w4 = *(const float4*)(wr + e);
      a += qq[e]*w4.x + qq[e+1]*w4.y + qq[e+2]*w4.z + qq[e+3]*w4.w;
    }
    a += __shfl_xor(a, 1); a += __shfl_xor(a, 2); a += __shfl_xor(a, 4);
    if (sub == 0) ws[FY2 + ((size_t)(b * 4 + c)) * DIM + d] = a + sbk[d];
  }
}

// ================= K2: LN finishers + seg softmax/gumbel masks =================
__global__ __launch_bounds__(256) void k_post(
    const float* __restrict__ slnqg, const float* __restrict__ slnqb,
    const float* __restrict__ rlnqg, const float* __restrict__ rlnqb,
    const float* __restrict__ rlnkg, const float* __restrict__ rlnkb,
    const float* __restrict__ slnkg, const float* __restrict__ slnkb,
    float* __restrict__ ws)
{
  const int b = blockIdx.x, tid = threadIdx.x;
  __shared__ float red[4];
  __shared__ float qps[DIM];
  __shared__ float lg[4];

  {
    float y[4];
    #pragma unroll
    for (int r = 0; r < 4; ++r) y[r] = ws[FYS + (size_t)b * DIM + tid + (r << 8)];
    float S = blk_sum(y[0]+y[1]+y[2]+y[3], red);
    float mu = S * (1.f / 1024.f);
    float pv = 0.f;
    #pragma unroll
    for (int r = 0; r < 4; ++r){ float dv = y[r]-mu; pv += dv*dv; }
    float V = blk_sum(pv, red);
    float sig = sqrtf(V * (1.f / 1024.f) + 1e-12f);
    #pragma unroll
    for (int r = 0; r < 4; ++r){
      const int d = tid + (r << 8);
      qps[d] = (y[r]-mu)/sig * slnqg[d] + slnqb[d];
    }
  }
  __syncthreads();

  {
    float y[4];
    #pragma unroll
    for (int r = 0; r < 4; ++r) y[r] = ws[FYR + (size_t)b * DIM + tid + (r << 8)];
    float S = blk_sum(y[0]+y[1]+y[2]+y[3], red);
    float mu = S * (1.f / 1024.f);
    float pv = 0.f;
    #pragma unroll
    for (int r = 0; r < 4; ++r){ float dv = y[r]-mu; pv += dv*dv; }
    float V = blk_sum(pv, red);
    float sig = sqrtf(V * (1.f / 1024.f) + 1e-12f);
    float sg = 0.f, cl = 0.f;
    #pragma unroll
    for (int r = 0; r < 4; ++r){
      const int d = tid + (r << 8);
      float o = (y[r]-mu)/sig * rlnqg[d] + rlnqb[d];
      float gv = rlnkg[d] * o;
      ws[FGQ + (size_t)b * DIM + d] = gv;
      sg += gv;
      cl += rlnkb[d] * o;
    }
    float SG = blk_sum(sg, red);
    float CL = blk_sum(cl, red);
    if (tid == 0){ ws[FSG + b] = SG; ws[FCL + b] = CL; }
  }

  for (int c = 0; c < 4; ++c){
    float y[4];
    #pragma unroll
    for (int r = 0; r < 4; ++r) y[r] = ws[FY2 + ((size_t)(b * 4 + c)) * DIM + tid + (r << 8)];
    float S = blk_sum(y[0]+y[1]+y[2]+y[3], red);
    float mu = S * (1.f / 1024.f);
    float pv = 0.f;
    #pragma unroll
    for (int r = 0; r < 4; ++r){ float dv = y[r]-mu; pv += dv*dv; }
    float V = blk_sum(pv, red);
    float sig = sqrtf(V * (1.f / 1024.f) + 1e-12f);
    float lp = 0.f;
    #pragma unroll
    for (int r = 0; r < 4; ++r){
      const int d = tid + (r << 8);
      float kp = (y[r]-mu)/sig * slnkg[d] + slnkb[d];
      lp += kp * qps[d];
    }
    float L = blk_sum(lp, red);
    if (tid == 0) lg[c] = L;
  }
  __syncthreads();

  if (tid == 0){
    float m = fmaxf(fmaxf(lg[0], lg[1]), fmaxf(lg[2], lg[3]));
    float e[4], s = 0.f;
    #pragma unroll
    for (int c = 0; c < 4; ++c){ e[c] = expf(lg[c] - m); s += e[c]; }
    float probs[4];
    #pragma unroll
    for (int c = 0; c < 4; ++c) probs[c] = e[c] / s;
    uint32_t k1a, k1b, k2a, k2b;
    jax_keys(k1a, k1b, k2a, k2b);
    for (int t = 0; t < 2; ++t){
      float x[4];
      #pragma unroll
      for (int c = 0; c < 4; ++c){
        float u = jax_uniform(k1a, k1b, (uint32_t)(b * 8 + t * 4 + c), 32u);
        float gmb = -logf(-logf(u));
        x[c] = (probs[c] + gmb) / 1e-6f;
      }
      float xm = fmaxf(fmaxf(x[0], x[1]), fmaxf(x[2], x[3]));
      float w[4], sw = 0.f;
      #pragma unroll
      for (int c = 0; c < 4; ++c){ w[c] = expf(x[c] - xm); sw += w[c]; }
      #pragma unroll
      for (int c = 0; c < 4; ++c) ws[FMS + b * 8 + t * 4 + c] = w[c] / sw;
    }
  }
}

// ================= K3: sel rows -> AI; tail: W -> WI (8 rows/block, fat) =======
__global__ __launch_bounds__(256) void k_sel(const float* __restrict__ E,
                                             const float* __restrict__ W,
                                             float* __restrict__ ws)
{
  const int blk = blockIdx.x;
  const int th = threadIdx.x;
  const int kc = th >> 3;              // 0..31
  const int c  = (th & 7) >> 1;        // 16B chunk within 32-elem half
  const int pos = (th & 1) * 4;
  const int d = th << 2;

  if (blk < 2048){
    const int r0 = blk * 8;            // 8 rows, all in pseudo-batch i
    const int i = r0 >> 8;
    const int bz = i >> 3, it = i & 7, t = it >> 2, j = it & 3;
    const int p0 = r0 & 255;
    const float* msk = ws + FMS + bz * 8 + t * 4;

    float4 a[8];
    #pragma unroll
    for (int r = 0; r < 8; ++r) a[r] = (float4){0.f, 0.f, 0.f, 0.f};

    #pragma unroll
    for (int cc = 0; cc < 4; ++cc){
      const float w = msk[cc];
      if (w != 0.f){
        const float* ep = E + (((size_t)((bz * 4 + cc) * 4 + j)) * 256 + p0) * DIM + d;
        #pragma unroll
        for (int r = 0; r < 8; ++r){
          const float4 v = *(const float4*)(ep + (size_t)r * DIM);
          a[r].x = fmaf(w, v.x, a[r].x);
          a[r].y = fmaf(w, v.y, a[r].y);
          a[r].z = fmaf(w, v.z, a[r].z);
          a[r].w = fmaf(w, v.w, a[r].w);
        }
      }
    }
    unsigned short* AI = (unsigned short*)ws + EAI;
    #pragma unroll
    for (int r = 0; r < 8; ++r){
      ushort4 h, l;
      h.x = f2h(a[r].x); l.x = f2h(a[r].x - h2f(h.x));
      h.y = f2h(a[r].y); l.y = f2h(a[r].y - h2f(h.y));
      h.z = f2h(a[r].z); l.z = f2h(a[r].z - h2f(h.z));
      h.w = f2h(a[r].w); l.w = f2h(a[r].w - h2f(h.w));
      const size_t base = (size_t)(r0 + r) * 2048 + kc * 64;
      *(ushort4*)&AI[base + c * 8 + pos]      = h;
      *(ushort4*)&AI[base + c * 8 + pos + 32] = l;
    }
  } else {
    const int r0 = (blk - 2048) * 8;   // 8 W rows
    unsigned short* WI = (unsigned short*)ws + EWI;
    float4 v[8];
    #pragma unroll
    for (int r = 0; r < 8; ++r)
      v[r] = *(const float4*)&W[(size_t)(r0 + r) * DIM + d];
    #pragma unroll
    for (int r = 0; r < 8; ++r){
      ushort4 h, l;
      h.x = f2h(v[r].x); l.x = f2h(v[r].x - h2f(h.x));
      h.y = f2h(v[r].y); l.y = f2h(v[r].y - h2f(h.y));
      h.z = f2h(v[r].z); l.z = f2h(v[r].z - h2f(h.z));
      h.w = f2h(v[r].w); l.w = f2h(v[r].w - h2f(h.w));
      const size_t base = (size_t)(r0 + r) * 2048 + kc * 64;
      *(ushort4*)&WI[base + c * 8 + pos]      = h;
      *(ushort4*)&WI[base + c * 8 + pos + 32] = l;
    }
  }
}

// ================= K4: split-fp16 MFMA GEMM, 256x256 tile, drift-phases ========
// Round-13 schedule (best measured: 84us, MfmaUtil 54%) — restored verbatim.
// Per-phase lgkmcnt(0)+sched_barrier pins + setprio, NO mid-kc barriers (waves
// drift); single end-of-kc lgkmcnt(0)+vmcnt(0)+barrier (round-9 race rule).
__global__ __launch_bounds__(512) void k_gemm(const float* __restrict__ bk,
                                              float* __restrict__ ws)
{
  const unsigned short* AI = (const unsigned short*)ws + EAI;
  const unsigned short* WI = (const unsigned short*)ws + EWI;
  const float* gq = ws + FGQ;
  float* part = ws + FPART;

  __shared__ __align__(16) unsigned short Abuf[2][16384];  // 2 x 256 x 64
  __shared__ __align__(16) unsigned short Bbuf[2][16384];  // 2 x 256 x 64

  const int bid = blockIdx.x;                 // 0..255
  const int xcd = bid & 7, g = bid >> 3;      // g 0..31
  const int rt = xcd * 8 + (g >> 2);          // 0..63
  const int ct = g & 3;                       // 0..3
  const int R0 = rt * 256, C0 = ct * 256;
  const int tid = threadIdx.x;
  const int lane = tid & 63, wid = tid >> 6;
  const int wr = wid >> 2, wc = wid & 3;      // 2 x 4 wave grid
  const int b = R0 >> 11;

  const int src_off = (lane >> 3) * 2048 + (((lane & 7) ^ (lane >> 3)) << 3);
  const int pcH = ((lane >> 4) ^ (lane & 7)) * 16;
  const int pcL = pcH ^ 64;
  const int raw = wr * 128 + (lane & 15);     // A row base in tile
  const int rbw = wc * 64 + (lane & 15);      // B row base in tile

  f32x4 acc[8][4];
  #pragma unroll
  for (int m = 0; m < 8; ++m)
    #pragma unroll
    for (int n = 0; n < 4; ++n)
      acc[m][n] = (f32x4){0.f, 0.f, 0.f, 0.f};

  auto stageA = [&](int buf, int kc){
    const unsigned short* As = AI + (size_t)(R0 + wid * 32) * 2048 + kc * 64 + src_off;
    unsigned short* Ad = &Abuf[buf][wid * 2048];
    #pragma unroll
    for (int q = 0; q < 4; ++q) gl_lds16(As + (size_t)q * 8 * 2048, Ad + q * 512);
  };
  auto stageB = [&](int buf, int kc){
    const unsigned short* Bs = WI + (size_t)(C0 + wid * 32) * 2048 + kc * 64 + src_off;
    unsigned short* Bd = &Bbuf[buf][wid * 2048];
    #pragma unroll
    for (int q = 0; q < 4; ++q) gl_lds16(Bs + (size_t)q * 8 * 2048, Bd + q * 512);
  };

  stageA(0, 0);
  stageB(0, 0);
  asm volatile("s_waitcnt vmcnt(0)" ::: "memory");
  __builtin_amdgcn_s_barrier();

  f16x8 ah[4], al[4], bh[4], bl[4];

  #pragma unroll 1
  for (int kc = 0; kc < 32; ++kc){
    const int cur = kc & 1;
    const char* pa = (const char*)&Abuf[cur][0];
    const char* pb = (const char*)&Bbuf[cur][0];

    // ---- phase 0: A fm0-3 + B fn0-1 reads; stage A(kc+1); MFMA (m0-3, n0-1)
    #pragma unroll
    for (int f = 0; f < 4; ++f){
      const int ro = (raw + f * 16) << 7;
      ah[f] = *(const f16x8*)(pa + ro + pcH);
      al[f] = *(const f16x8*)(pa + ro + pcL);
    }
    #pragma unroll
    for (int f = 0; f < 2; ++f){
      const int ro = (rbw + f * 16) << 7;
      bh[f] = *(const f16x8*)(pb + ro + pcH);
      bl[f] = *(const f16x8*)(pb + ro + pcL);
    }
    if (kc < 31) stageA(cur ^ 1, kc + 1);
    asm volatile("s_waitcnt lgkmcnt(0)" ::: "memory");
    __builtin_amdgcn_sched_barrier(0);
    __builtin_amdgcn_s_setprio(1);
    #pragma unroll
    for (int m = 0; m < 4; ++m)
      #pragma unroll
      for (int n = 0; n < 2; ++n){
        acc[m][n] = __builtin_amdgcn_mfma_f32_16x16x32_f16(ah[m], bh[n], acc[m][n], 0, 0, 0);
        acc[m][n] = __builtin_amdgcn_mfma_f32_16x16x32_f16(ah[m], bl[n], acc[m][n], 0, 0, 0);
        acc[m][n] = __builtin_amdgcn_mfma_f32_16x16x32_f16(al[m], bh[n], acc[m][n], 0, 0, 0);
      }
    __builtin_amdgcn_s_setprio(0);

    // ---- phase 1: B fn2-3 reads; stage B(kc+1); MFMA (m0-3, n2-3)
    #pragma unroll
    for (int f = 2; f < 4; ++f){
      const int ro = (rbw + f * 16) << 7;
      bh[f] = *(const f16x8*)(pb + ro + pcH);
      bl[f] = *(const f16x8*)(pb + ro + pcL);
    }
    if (kc < 31) stageB(cur ^ 1, kc + 1);
    asm volatile("s_waitcnt lgkmcnt(0)" ::: "memory");
    __builtin_amdgcn_sched_barrier(0);
    __builtin_amdgcn_s_setprio(1);
    #pragma unroll
    for (int m = 0; m < 4; ++m)
      #pragma unroll
      for (int n = 2; n < 4; ++n){
        acc[m][n] = __builtin_amdgcn_mfma_f32_16x16x32_f16(ah[m], bh[n], acc[m][n], 0, 0, 0);
        acc[m][n] = __builtin_amdgcn_mfma_f32_16x16x32_f16(ah[m], bl[n], acc[m][n], 0, 0, 0);
        acc[m][n] = __builtin_amdgcn_mfma_f32_16x16x32_f16(al[m], bh[n], acc[m][n], 0, 0, 0);
      }
    __builtin_amdgcn_s_setprio(0);

    // ---- phase 2: A fm4-7 reads (overwrite ah/al); MFMA (m4-7, n0-1)
    #pragma unroll
    for (int f = 0; f < 4; ++f){
      const int ro = (raw + 64 + f * 16) << 7;
      ah[f] = *(const f16x8*)(pa + ro + pcH);
      al[f] = *(const f16x8*)(pa + ro + pcL);
    }
    asm volatile("s_waitcnt lgkmcnt(0)" ::: "memory");
    __builtin_amdgcn_sched_barrier(0);
    __builtin_amdgcn_s_setprio(1);
    #pragma unroll
    for (int m = 0; m < 4; ++m)
      #pragma unroll
      for (int n = 0; n < 2; ++n){
        acc[m + 4][n] = __builtin_amdgcn_mfma_f32_16x16x32_f16(ah[m], bh[n], acc[m + 4][n], 0, 0, 0);
        acc[m + 4][n] = __builtin_amdgcn_mfma_f32_16x16x32_f16(ah[m], bl[n], acc[m + 4][n], 0, 0, 0);
        acc[m + 4][n] = __builtin_amdgcn_mfma_f32_16x16x32_f16(al[m], bh[n], acc[m + 4][n], 0, 0, 0);
      }
    __builtin_amdgcn_s_setprio(0);

    // ---- phase 3: MFMA (m4-7, n2-3); kc-end drain + ONE barrier
    __builtin_amdgcn_s_setprio(1);
    #pragma unroll
    for (int m = 0; m < 4; ++m)
      #pragma unroll
      for (int n = 2; n < 4; ++n){
        acc[m + 4][n] = __builtin_amdgcn_mfma_f32_16x16x32_f16(ah[m], bh[n], acc[m + 4][n], 0, 0, 0);
        acc[m + 4][n] = __builtin_amdgcn_mfma_f32_16x16x32_f16(ah[m], bl[n], acc[m + 4][n], 0, 0, 0);
        acc[m + 4][n] = __builtin_amdgcn_mfma_f32_16x16x32_f16(al[m], bh[n], acc[m + 4][n], 0, 0, 0);
      }
    __builtin_amdgcn_s_setprio(0);
    asm volatile("s_waitcnt lgkmcnt(0)" ::: "memory");  // all this wave's LDS reads done
    __builtin_amdgcn_sched_barrier(0);
    asm volatile("s_waitcnt vmcnt(0)" ::: "memory");    // kc+1 stages landed
    __builtin_amdgcn_s_barrier();
  }

  // epilogue: per-row stats (sum over this ct-tile's 256 cols)
  float bkv[4], gv[4];
  #pragma unroll
  for (int n = 0; n < 4; ++n){
    const int col = C0 + wc * 64 + n * 16 + (lane & 15);
    bkv[n] = bk[col];
    gv[n]  = gq[(size_t)b * DIM + col];
  }
  float* fred = (float*)&Abuf[0][0];   // 256*4*3 floats = 12KB, overlays Abuf
  #pragma unroll
  for (int m = 0; m < 8; ++m)
    #pragma unroll
    for (int r = 0; r < 4; ++r){
      float s = 0.f, q = 0.f, tv = 0.f;
      #pragma unroll
      for (int n = 0; n < 4; ++n){
        float y = acc[m][n][r] + bkv[n];
        s += y; q += y * y; tv += y * gv[n];
      }
      #pragma unroll
      for (int msk = 8; msk >= 1; msk >>= 1){
        s += __shfl_xor(s, msk); q += __shfl_xor(q, msk); tv += __shfl_xor(tv, msk);
      }
      if ((lane & 15) == 0){
        const int rl = wr * 128 + m * 16 + (lane >> 4) * 4 + r;
        fred[(rl * 4 + wc) * 3 + 0] = s;
        fred[(rl * 4 + wc) * 3 + 1] = q;
        fred[(rl * 4 + wc) * 3 + 2] = tv;
      }
    }
  __syncthreads();
  if (tid < 256){
    #pragma unroll
    for (int st = 0; st < 3; ++st){
      float v = fred[(tid * 4 + 0) * 3 + st] + fred[(tid * 4 + 1) * 3 + st]
              + fred[(tid * 4 + 2) * 3 + st] + fred[(tid * 4 + 3) * 3 + st];
      part[((size_t)ct * NROW + R0 + tid) * 3 + st] = v;
    }
  }
}

// ================= K5: probs2 (once) + 4x (gumbel + gather) -> out =============
// Fattened: one block handles 4 consecutive t2 of one i (grid 8192 -> 2048),
// computing the probs2 softmax ONCE and amortizing part[] reads + launch
// overhead 4x. wv/mk reuse across sub-iterations is fenced by the reductions'
// entry barriers.
__global__ __launch_bounds__(256) void k_out(const float* __restrict__ E,
                                             const float* __restrict__ ws,
                                             float* __restrict__ out)
{
  const int bid = blockIdx.x;           // 0..2047
  const int i = bid >> 5, tg = (bid & 31) << 2;   // t2 in [tg, tg+4)
  const int bz = i >> 3, it = i & 7, tt = it >> 2, j = it & 3;
  const int tid = threadIdx.x;
  __shared__ float red[4];
  __shared__ float wv[256];
  __shared__ float mloc[4];
  __shared__ unsigned long long mk[4];

  if (tid < 4) mloc[tid] = ws[FMS + bz * 8 + tt * 4 + tid];

  // --- probs2 recompute (once per block) ---
  const float* part = ws + FPART;
  const int r = i * 256 + tid;
  float S = 0.f, Q = 0.f, T = 0.f;
  #pragma unroll
  for (int ct = 0; ct < NCT; ++ct){
    const float* pp = part + ((size_t)ct * NROW + r) * 3;
    S += pp[0]; Q += pp[1]; T += pp[2];
  }
  float mu  = S * (1.f / 1024.f);
  float var = Q * (1.f / 1024.f) - mu * mu;
  float sig = sqrtf(var + 1e-12f);
  float L = (T - mu * ws[FSG + bz]) / sig + ws[FCL + bz];
  float ML = blk_max(L, red);
  float wp2 = expf(L - ML);
  float swp = blk_sum(wp2, red);
  float p2 = wp2 / swp;

  uint32_t k1a, k1b, k2a, k2b;
  jax_keys(k1a, k1b, k2a, k2b);
  const int d = tid << 2;

  #pragma unroll 1
  for (int s = 0; s < 4; ++s){
    const int t2 = tg + s;
    const uint32_t fidx = ((uint32_t)(i * TOPJ + t2)) * 256u + (uint32_t)tid;
    float u = jax_uniform(k2a, k2b, fidx, 1048576u);
    float gmb = -logf(-logf(u));
    float x = (p2 + gmb) / 1e-6f;
    float M = blk_max(x, red);           // entry barrier also fences wv reuse
    float w = expf(x - M);
    float sw = blk_sum(w, red);
    float wn = w / sw;
    wv[tid] = wn;
    unsigned long long bal = __ballot(wn != 0.f);
    if ((tid & 63) == 0) mk[tid >> 6] = bal;
    __syncthreads();

    float4 acc = {0.f, 0.f, 0.f, 0.f};
    for (int wq = 0; wq < 4; ++wq){
      unsigned long long mm = mk[wq];
      while (mm){
        const int l = __ffsll(mm) - 1;
        mm &= mm - 1;
        const int p = (wq << 6) + l;
        const float wpv = wv[p];
        #pragma unroll
        for (int c = 0; c < 4; ++c){
          const float mc = mloc[c];
          if (mc != 0.f){
            const float4 v = *(const float4*)&E[(((size_t)((bz * 4 + c) * 4 + j)) * 256 + p) * DIM + d];
            const float wm = wpv * mc;
            acc.x += wm * v.x; acc.y += wm * v.y; acc.z += wm * v.z; acc.w += wm * v.w;
          }
        }
      }
    }
    *(float4*)&out[((size_t)(i * TOPJ + t2)) * DIM + d] = acc;
  }
}

// ---------------- launch ----------------
extern "C" void kernel_launch(void* const* d_in, const int* in_sizes, int n_in,
                              void* d_out, int out_size, void* d_ws, size_t ws_size,
                              hipStream_t stream)
{
  const float* qf    = (const float*)d_in[0];
  const float* E     = (const float*)d_in[1];
  const float* vcls  = (const float*)d_in[2];
  const float* sWq   = (const float*)d_in[3];
  const float* sbq   = (const float*)d_in[4];
  const float* slnqg = (const float*)d_in[5];
  const float* slnqb = (const float*)d_in[6];
  const float* sWk   = (const float*)d_in[7];
  const float* sbk   = (const float*)d_in[8];
  const float* slnkg = (const float*)d_in[9];
  const float* slnkb = (const float*)d_in[10];
  const float* rWq   = (const float*)d_in[11];
  const float* rbq   = (const float*)d_in[12];
  const float* rlnqg = (const float*)d_in[13];
  const float* rlnqb = (const float*)d_in[14];
  const float* rWk   = (const float*)d_in[15];
  const float* rbk   = (const float*)d_in[16];
  const float* rlnkg = (const float*)d_in[17];
  const float* rlnkb = (const float*)d_in[18];
  float* ws  = (float*)d_ws;
  float* out = (float*)d_out;

  k_matvec<<<256, 256, 0, stream>>>(qf, vcls, sWq, sbq, rWq, rbq, sWk, sbk, ws);
  k_post<<<BZ, 256, 0, stream>>>(slnqg, slnqb, rlnqg, rlnqb, rlnkg, rlnkb, slnkg, slnkb, ws);
  k_sel<<<2176, 256, 0, stream>>>(E, rWk, ws);
  k_gemm<<<256, 512, 0, stream>>>(rbk, ws);
  k_out<<<2048, 256, 0, stream>>>(E, ws, out);
}